// Round 3
// baseline (1308.746 us; speedup 1.0000x reference)
//
#include <hip/hip_runtime.h>
#include <hip/hip_bf16.h>
#include <cstdint>
#include <cmath>

typedef __bf16 bf16;
typedef __bf16 bf16x8 __attribute__((ext_vector_type(8)));
typedef __bf16 bf16x4 __attribute__((ext_vector_type(4)));
typedef float f32x4 __attribute__((ext_vector_type(4)));

#define NROWS 8192
#define UNITS 2048
#define NT 64      // K = 4096 / BK(=64)
#define NSPLIT 32  // tile index where A switches from A0 to A1

__device__ __forceinline__ void gload_lds16(const bf16* g, const bf16* lds) {
  __builtin_amdgcn_global_load_lds(
      (const __attribute__((address_space(1))) uint32_t*)(uintptr_t)g,
      (__attribute__((address_space(3))) uint32_t*)(uint32_t)(uintptr_t)lds,
      16, 0, 0);
}

#define BARR do { asm volatile("" ::: "memory"); __builtin_amdgcn_s_barrier(); \
                  __builtin_amdgcn_sched_barrier(0); asm volatile("" ::: "memory"); } while (0)
#define WAITV6  asm volatile("s_waitcnt vmcnt(6)" ::: "memory")
#define WAITV12 asm volatile("s_waitcnt vmcnt(12)" ::: "memory")

// ---- pack x,y fp32 -> bf16
__global__ void pack_xy_kernel(const float* __restrict__ x, const float* __restrict__ y,
                               bf16* __restrict__ xb, bf16* __restrict__ yb) {
  size_t n4 = (size_t)NROWS * UNITS / 4;
  size_t stride = (size_t)gridDim.x * blockDim.x;
  for (size_t i = (size_t)blockIdx.x * blockDim.x + threadIdx.x; i < n4; i += stride) {
    float4 vx = ((const float4*)x)[i];
    float4 vy = ((const float4*)y)[i];
    bf16x4 ox = {(bf16)vx.x, (bf16)vx.y, (bf16)vx.z, (bf16)vx.w};
    bf16x4 oy = {(bf16)vy.x, (bf16)vy.y, (bf16)vy.z, (bf16)vy.w};
    ((bf16x4*)xb)[i] = ox;
    ((bf16x4*)yb)[i] = oy;
  }
}

// ---- tiled transpose + convert
__global__ void transpose_cvt_kernel(const float* __restrict__ src, bf16* __restrict__ dst,
                                     int ldd, int koff) {
  __shared__ float t[32][33];
  int j0 = blockIdx.x * 32, k0 = blockIdx.y * 32;
  int tx = threadIdx.x & 31, ty = threadIdx.x >> 5;
#pragma unroll
  for (int i = 0; i < 32; i += 8)
    t[ty + i][tx] = src[(size_t)(k0 + ty + i) * UNITS + j0 + tx];
  __syncthreads();
#pragma unroll
  for (int i = 0; i < 32; i += 8)
    dst[(size_t)(j0 + ty + i) * ldd + koff + k0 + tx] = (bf16)t[tx][ty + i];
}

// ================= 256x256 read-ahead 4-phase GEMM, C = A @ Bt^T =================
template <int EPI>
__global__ __launch_bounds__(512)
void gemm256(const bf16* __restrict__ A0, const bf16* __restrict__ A1,
             const bf16* __restrict__ Bt,
             const float* __restrict__ bias_a, const float* __restrict__ bias_b,
             const float* __restrict__ bias_c, const float* __restrict__ bias_d,
             const float* __restrict__ xin, float* __restrict__ zbuf,
             bf16* __restrict__ rxbuf, float* __restrict__ outbuf) {
  __shared__ bf16 LDS[2][32768];  // per buf: A[0,16384) B[16384,32768)
  const int tid = threadIdx.x;
  const int wv = tid >> 6, lane = tid & 63;
  const int wr = wv >> 2, wc = wv & 3;

  const int nwg = gridDim.x;
  const int bs = ((int)blockIdx.x & 7) * (nwg >> 3) + ((int)blockIdx.x >> 3);
  const int by = bs & 31;  // NROWS/256 = 32
  const int bx = bs >> 5;
  const int brow = by * 256;
  const int bcol = bx * 256;

  // ---- staging offsets. Halves aligned with read quadrants:
  // A region r (r*8192): rows r*128.., subtile ss: rows (ss>>1)*16, khalf ss&1.
  // ST_A H stages subtiles H*8+wv of both regions; ST_B H stages (wv>>2)*8+H*4+(wv&3).
  const int rr = lane >> 2;
  const int kk_st = ((lane & 3) * 8) ^ ((rr & 6) << 2);  // inverse-swizzled source k
  int offA[2][2], offB[2][2], dstA[2][2], dstB[2][2];
#pragma unroll
  for (int H = 0; H < 2; ++H)
#pragma unroll
    for (int c = 0; c < 2; ++c) {
      int ssA = H * 8 + wv;
      offA[H][c] = (brow + c * 128 + (ssA >> 1) * 16 + rr) * 2048 + (ssA & 1) * 32 + kk_st;
      dstA[H][c] = c * 8192 + ssA * 512;
      int ssB = (wv >> 2) * 8 + H * 4 + (wv & 3);
      offB[H][c] = (bcol + c * 128 + (ssB >> 1) * 16 + rr) * 4096 + (ssB & 1) * 32 + kk_st;
      dstB[H][c] = 16384 + c * 8192 + ssB * 512;
    }

  // ---- fragment read offsets (swizzled)
  const int lr = lane & 15;
  const int kread = ((lane >> 4) * 8) ^ ((lr & 6) << 2);
  const int abase = wr * 8192 + lr * 32 + kread;
  const int bbase = 16384 + (wc >> 1) * 8192 + (wc & 1) * 4096 + lr * 32 + kread;

#define ST_A(TI, H, BUF)                                                      \
  if ((TI) < NT) {                                                            \
    const bf16* _s = ((TI) < NSPLIT) ? A0 + (size_t)(TI)*64                   \
                                     : A1 + (size_t)((TI)-NSPLIT) * 64;       \
    gload_lds16(_s + offA[H][0], (BUF) + dstA[H][0]);                         \
    gload_lds16(_s + offA[H][1], (BUF) + dstA[H][1]);                         \
  }
#define ST_B(TI, H, BUF)                                                      \
  if ((TI) < NT) {                                                            \
    const bf16* _s = Bt + (size_t)(TI)*64;                                    \
    gload_lds16(_s + offB[H][0], (BUF) + dstB[H][0]);                         \
    gload_lds16(_s + offB[H][1], (BUF) + dstB[H][1]);                         \
  }
#define RD_B(DST, LP, NB)                                                     \
  _Pragma("unroll") for (int n = 0; n < 2; ++n)                               \
  _Pragma("unroll") for (int kh = 0; kh < 2; ++kh)                            \
      DST[n][kh] = *(const bf16x8*)((LP) + bbase + ((n + 2 * (NB)) * 2 + kh) * 512);
#define RD_A(DST, LP, MB)                                                     \
  _Pragma("unroll") for (int m = 0; m < 4; ++m)                               \
  _Pragma("unroll") for (int kh = 0; kh < 2; ++kh)                            \
      DST[m][kh] = *(const bf16x8*)((LP) + abase + ((m + 4 * (MB)) * 2 + kh) * 512);
#define MFMA_Q(AARR, BARR_, MOFF, NOFF)                                       \
  __builtin_amdgcn_s_setprio(1);                                              \
  _Pragma("unroll") for (int kh = 0; kh < 2; ++kh)                            \
  _Pragma("unroll") for (int m = 0; m < 4; ++m)                               \
  _Pragma("unroll") for (int n = 0; n < 2; ++n)                               \
      acc[m + MOFF][n + NOFF] = __builtin_amdgcn_mfma_f32_16x16x32_bf16(      \
          AARR[m][kh], BARR_[n][kh], acc[m + MOFF][n + NOFF], 0, 0, 0);       \
  __builtin_amdgcn_s_setprio(0);

  f32x4 acc[8][4];
#pragma unroll
  for (int m = 0; m < 8; ++m)
#pragma unroll
    for (int n = 0; n < 4; ++n) {
      f32x4 zz = {0.f, 0.f, 0.f, 0.f};
      acc[m][n] = zz;
    }

  bf16x8 a0[4][2], a1[4][2], b0a[2][2], b0b[2][2], b1[2][2];

  // ---- prologue: emulate steady-state issue order for tiles 0,1 ----
  {
    bf16* L0 = &LDS[0][0];
    bf16* L1 = &LDS[1][0];
    ST_B(0, 0, L0); ST_A(0, 0, L0); ST_B(0, 1, L0); ST_A(0, 1, L0);
    ST_B(1, 0, L1);
    ST_A(1, 0, L1); ST_B(1, 1, L1); ST_A(1, 1, L1);
    WAITV12;  // confirms B_h0(0), A_h0(0)
    BARR;
    RD_B(b0a, L0, 0);
    RD_A(a0, L0, 0);
    WAITV6;  // confirms B_h1(0), A_h1(0), B_h0(1); leaves {A_h0(1),B_h1(1),A_h1(1)}
    BARR;
  }

#define TILE(T, CUR, NXT, B0USE, B0LD)                                        \
  {                                                                           \
    const bf16* Lc = &LDS[CUR][0];                                            \
    bf16* Lcw = &LDS[CUR][0];                                                 \
    const bf16* Ln = &LDS[NXT][0];                                            \
    /* P1: read b1(t); stage B_h0(t+2)->C; MFMA a0*b0 */                      \
    RD_B(b1, Lc, 1);                                                          \
    ST_B((T) + 2, 0, Lcw);                                                    \
    MFMA_Q(a0, B0USE, 0, 0);                                                  \
    WAITV6; BARR;                                                             \
    /* P2: read a1(t); stage A_h0(t+2)->C; MFMA a0*b1 */                      \
    RD_A(a1, Lc, 1);                                                          \
    ST_A((T) + 2, 0, Lcw);                                                    \
    MFMA_Q(a0, b1, 0, 2);                                                     \
    WAITV6; BARR;                                                             \
    /* P3: read b0(t+1) from N; stage B_h1(t+2)->C; MFMA a1*b0 */             \
    if ((T) + 1 < NT) { RD_B(B0LD, Ln, 0); }                                  \
    ST_B((T) + 2, 1, Lcw);                                                    \
    MFMA_Q(a1, B0USE, 4, 0);                                                  \
    WAITV6; BARR;                                                             \
    /* P4: read a0(t+1) from N; stage A_h1(t+2)->C; MFMA a1*b1 */             \
    if ((T) + 1 < NT) { RD_A(a0, Ln, 0); }                                    \
    ST_A((T) + 2, 1, Lcw);                                                    \
    MFMA_Q(a1, b1, 4, 2);                                                     \
    WAITV6; BARR;                                                             \
  }

#pragma unroll 1
  for (int t = 0; t < NT; t += 2) {
    TILE(t, 0, 1, b0a, b0b);
    TILE(t + 1, 1, 0, b0b, b0a);
  }

  // ---- epilogue: C/D layout col=lane&15, row=(lane>>4)*4+q ----
  const int lq = (lane >> 4) << 2;
  const int lc = lane & 15;
  const int rowb = brow + wr * 128;
  const int colb = bcol + wc * 64;
  if constexpr (EPI == 0) {
    if (bcol < UNITS) {
#pragma unroll
      for (int m = 0; m < 8; ++m)
#pragma unroll
        for (int n = 0; n < 4; ++n) {
          int col = colb + n * 16 + lc;
          float ba = bias_a[col] + bias_b[col];
#pragma unroll
          for (int q = 0; q < 4; ++q) {
            int row = rowb + m * 16 + lq + q;
            zbuf[(size_t)row * UNITS + col] = acc[m][n][q] + ba;
          }
        }
    } else {
#pragma unroll
      for (int m = 0; m < 8; ++m)
#pragma unroll
        for (int n = 0; n < 4; ++n) {
          int col = colb - UNITS + n * 16 + lc;
          float bc = bias_c[col] + bias_d[col];
#pragma unroll
          for (int q = 0; q < 4; ++q) {
            int row = rowb + m * 16 + lq + q;
            size_t idx = (size_t)row * UNITS + col;
            float r = acc[m][n][q] + bc;
            rxbuf[idx] = (bf16)(r * xin[idx]);
          }
        }
    }
  } else {
#pragma unroll
    for (int m = 0; m < 8; ++m)
#pragma unroll
      for (int n = 0; n < 4; ++n) {
        int col = colb + n * 16 + lc;
        float bg_ = bias_a[col] + bias_b[col];
#pragma unroll
        for (int q = 0; q < 4; ++q) {
          int row = rowb + m * 16 + lq + q;
          size_t idx = (size_t)row * UNITS + col;
          float h = tanhf(acc[m][n][q] + bg_);
          float zv = zbuf[idx];
          float xv = xin[idx];
          outbuf[idx] = (1.f - zv) * xv + zv * h;
        }
      }
  }
#undef ST_A
#undef ST_B
#undef RD_A
#undef RD_B
#undef MFMA_Q
#undef TILE
}

extern "C" void kernel_launch(void* const* d_in, const int* in_sizes, int n_in,
                              void* d_out, int out_size, void* d_ws, size_t ws_size,
                              hipStream_t stream) {
  const float* x   = (const float*)d_in[0];
  const float* y   = (const float*)d_in[1];
  const float* Wz  = (const float*)d_in[2];
  const float* bz  = (const float*)d_in[3];
  const float* Uz  = (const float*)d_in[4];
  const float* buz = (const float*)d_in[5];
  const float* Wr  = (const float*)d_in[6];
  const float* br  = (const float*)d_in[7];
  const float* Ur  = (const float*)d_in[8];
  const float* bur = (const float*)d_in[9];
  const float* Wg  = (const float*)d_in[10];
  const float* bg  = (const float*)d_in[11];
  const float* Ug  = (const float*)d_in[12];
  const float* bug = (const float*)d_in[13];
  float* out = (float*)d_out;

  char* w = (char*)d_ws;
  bf16* Ybf = (bf16*)w;  w += (size_t)NROWS * UNITS * 2;  // 32 MiB
  bf16* Xbf = (bf16*)w;  w += (size_t)NROWS * UNITS * 2;  // 32 MiB
  bf16* RX  = (bf16*)w;  w += (size_t)NROWS * UNITS * 2;  // 32 MiB
  bf16* Bzr = (bf16*)w;  w += (size_t)4096 * 4096 * 2;    // 32 MiB [4096 cols][K=4096]
  bf16* Bgt = (bf16*)w;  w += (size_t)2048 * 4096 * 2;    // 16 MiB [2048 cols][K=4096]
  float* Zb = (float*)w; w += (size_t)NROWS * UNITS * 4;  // 64 MiB

  pack_xy_kernel<<<2048, 256, 0, stream>>>(x, y, Xbf, Ybf);

  dim3 tg(64, 64);
  transpose_cvt_kernel<<<tg, 256, 0, stream>>>(Wz, Bzr, 4096, 0);
  transpose_cvt_kernel<<<tg, 256, 0, stream>>>(Uz, Bzr, 4096, 2048);
  transpose_cvt_kernel<<<tg, 256, 0, stream>>>(Wr, Bzr + (size_t)2048 * 4096, 4096, 0);
  transpose_cvt_kernel<<<tg, 256, 0, stream>>>(Ur, Bzr + (size_t)2048 * 4096, 4096, 2048);
  transpose_cvt_kernel<<<tg, 256, 0, stream>>>(Wg, Bgt, 4096, 0);
  transpose_cvt_kernel<<<tg, 256, 0, stream>>>(Ug, Bgt, 4096, 2048);

  // GEMM1: [8192 x 4096] = [Y|X] @ Bzr^T -> z (fp32), rx (bf16)
  gemm256<0><<<512, 512, 0, stream>>>(Ybf, Xbf, Bzr, bz, buz, br, bur, x, Zb, RX, nullptr);
  // GEMM2: [8192 x 2048] = [Y|RX] @ Bg^T -> out
  gemm256<1><<<256, 512, 0, stream>>>(Ybf, RX, Bgt, bg, bug, nullptr, nullptr, x, Zb, nullptr, out);
}

// Round 4
// 503.810 us; speedup vs baseline: 2.5977x; 2.5977x over previous
//
#include <hip/hip_runtime.h>
#include <hip/hip_bf16.h>
#include <cstdint>
#include <cmath>

typedef __bf16 bf16;
typedef __bf16 bf16x8 __attribute__((ext_vector_type(8)));
typedef __bf16 bf16x4 __attribute__((ext_vector_type(4)));
typedef float f32x4 __attribute__((ext_vector_type(4)));

#define NROWS 8192
#define UNITS 2048
#define NT 64      // K = 4096 / BK(=64)
#define NSPLIT 32  // tile index where A switches from A0 to A1

__device__ __forceinline__ void gload_lds16(const bf16* g, const bf16* lds) {
  __builtin_amdgcn_global_load_lds(
      (const __attribute__((address_space(1))) uint32_t*)(uintptr_t)g,
      (__attribute__((address_space(3))) uint32_t*)(uint32_t)(uintptr_t)lds,
      16, 0, 0);
}

#define BARR do { asm volatile("" ::: "memory"); __builtin_amdgcn_s_barrier(); \
                  asm volatile("" ::: "memory"); } while (0)
#define WAITV4 asm volatile("s_waitcnt vmcnt(4)" ::: "memory")
#define LGKM8  asm volatile("s_waitcnt lgkmcnt(8)" ::: "memory")
#define LGKM0  asm volatile("s_waitcnt lgkmcnt(0)" ::: "memory")

// ---- pack x,y fp32 -> bf16
__global__ void pack_xy_kernel(const float* __restrict__ x, const float* __restrict__ y,
                               bf16* __restrict__ xb, bf16* __restrict__ yb) {
  size_t n4 = (size_t)NROWS * UNITS / 4;
  size_t stride = (size_t)gridDim.x * blockDim.x;
  for (size_t i = (size_t)blockIdx.x * blockDim.x + threadIdx.x; i < n4; i += stride) {
    float4 vx = ((const float4*)x)[i];
    float4 vy = ((const float4*)y)[i];
    bf16x4 ox = {(bf16)vx.x, (bf16)vx.y, (bf16)vx.z, (bf16)vx.w};
    bf16x4 oy = {(bf16)vy.x, (bf16)vy.y, (bf16)vy.z, (bf16)vy.w};
    ((bf16x4*)xb)[i] = ox;
    ((bf16x4*)yb)[i] = oy;
  }
}

// ---- fused 6-way transpose+convert: z selects (src, dst, koff)
__global__ void transpose_cvt6_kernel(const float* __restrict__ Wz, const float* __restrict__ Uz,
                                      const float* __restrict__ Wr, const float* __restrict__ Ur,
                                      const float* __restrict__ Wg, const float* __restrict__ Ug,
                                      bf16* __restrict__ Bzr, bf16* __restrict__ Bgt) {
  __shared__ float t[32][33];
  const float* src;
  bf16* dst;
  int koff;
  switch (blockIdx.z) {
    case 0: src = Wz; dst = Bzr;                         koff = 0;    break;
    case 1: src = Uz; dst = Bzr;                         koff = 2048; break;
    case 2: src = Wr; dst = Bzr + (size_t)2048 * 4096;   koff = 0;    break;
    case 3: src = Ur; dst = Bzr + (size_t)2048 * 4096;   koff = 2048; break;
    case 4: src = Wg; dst = Bgt;                         koff = 0;    break;
    default: src = Ug; dst = Bgt;                        koff = 2048; break;
  }
  int j0 = blockIdx.x * 32, k0 = blockIdx.y * 32;
  int tx = threadIdx.x & 31, ty = threadIdx.x >> 5;
#pragma unroll
  for (int i = 0; i < 32; i += 8)
    t[ty + i][tx] = src[(size_t)(k0 + ty + i) * UNITS + j0 + tx];
  __syncthreads();
#pragma unroll
  for (int i = 0; i < 32; i += 8)
    dst[(size_t)(j0 + ty + i) * 4096 + koff + k0 + tx] = (bf16)t[tx][ty + i];
}

// ================= 256x256 4-phase GEMM (m201-style), C = A @ Bt^T =================
// A = [A0 | A1] along K (each lda=2048), Bt row-major [Ncols][4096].
// EPI 0: cols<2048 -> z=acc+ba+bb (bf16 zbuf); cols>=2048 -> rx=(acc+bc+bd)*x (bf16)
// EPI 1: out = (1-z)*x + z*tanh(acc+ba+bb)
template <int EPI>
__global__ __launch_bounds__(512, 2)
void gemm256(const bf16* __restrict__ A0, const bf16* __restrict__ A1,
             const bf16* __restrict__ Bt,
             const float* __restrict__ bias_a, const float* __restrict__ bias_b,
             const float* __restrict__ bias_c, const float* __restrict__ bias_d,
             const float* __restrict__ xin, bf16* __restrict__ zbuf,
             bf16* __restrict__ rxbuf, float* __restrict__ outbuf) {
  __shared__ bf16 LDS[2][32768];  // per buf: A[0,16384) B[16384,32768)
  const int tid = threadIdx.x;
  const int wv = tid >> 6, lane = tid & 63;
  const int wr = wv >> 2, wc = wv & 3;

  // 2-D XCD patch mapping: each XCD owns a 16(by) x (nl/16)(bx) patch ->
  // A panels and B panels both reused within the XCD's L2.
  const int nl = (int)gridDim.x >> 3;  // blocks per XCD
  const int xc = (int)blockIdx.x & 7;
  const int l = (int)blockIdx.x >> 3;
  const int bxq = nl >> 4;
  const int by = (xc & 1) * 16 + (l & 15);
  const int bx = (xc >> 1) * bxq + (l >> 4);
  const int brow = by * 256;
  const int bcol = bx * 256;

  // ---- staging offsets; halves aligned with read quadrants.
  const int rr = lane >> 2;
  const int kk_st = ((lane & 3) * 8) ^ ((rr & 6) << 2);  // inverse-swizzled source k
  int offA[2][2], offB[2][2], dstA[2][2], dstB[2][2];
#pragma unroll
  for (int H = 0; H < 2; ++H)
#pragma unroll
    for (int c = 0; c < 2; ++c) {
      int ssA = H * 8 + wv;
      offA[H][c] = (brow + c * 128 + (ssA >> 1) * 16 + rr) * 2048 + (ssA & 1) * 32 + kk_st;
      dstA[H][c] = c * 8192 + ssA * 512;
      int ssB = (wv >> 2) * 8 + H * 4 + (wv & 3);
      offB[H][c] = (bcol + c * 128 + (ssB >> 1) * 16 + rr) * 4096 + (ssB & 1) * 32 + kk_st;
      dstB[H][c] = 16384 + c * 8192 + ssB * 512;
    }

  // ---- fragment read offsets (swizzled)
  const int lr = lane & 15;
  const int kread = ((lane >> 4) * 8) ^ ((lr & 6) << 2);
  const int abase = wr * 8192 + lr * 32 + kread;
  const int bbase = 16384 + (wc >> 1) * 8192 + (wc & 1) * 4096 + lr * 32 + kread;

#define ST_A(TI, H, BUF)                                                      \
  if ((TI) < NT) {                                                            \
    const bf16* _s = ((TI) < NSPLIT) ? A0 + (size_t)(TI)*64                   \
                                     : A1 + (size_t)((TI)-NSPLIT) * 64;       \
    gload_lds16(_s + offA[H][0], (BUF) + dstA[H][0]);                         \
    gload_lds16(_s + offA[H][1], (BUF) + dstA[H][1]);                         \
  }
#define ST_B(TI, H, BUF)                                                      \
  if ((TI) < NT) {                                                            \
    const bf16* _s = Bt + (size_t)(TI)*64;                                    \
    gload_lds16(_s + offB[H][0], (BUF) + dstB[H][0]);                         \
    gload_lds16(_s + offB[H][1], (BUF) + dstB[H][1]);                         \
  }
#define RD_B(DST, LP, NB)                                                     \
  _Pragma("unroll") for (int n = 0; n < 2; ++n)                               \
  _Pragma("unroll") for (int kh = 0; kh < 2; ++kh)                            \
      DST[n][kh] = *(const bf16x8*)((LP) + bbase + ((n + 2 * (NB)) * 2 + kh) * 512);
#define RD_A(DST, LP, MB)                                                     \
  _Pragma("unroll") for (int m = 0; m < 4; ++m)                               \
  _Pragma("unroll") for (int kh = 0; kh < 2; ++kh)                            \
      DST[m][kh] = *(const bf16x8*)((LP) + abase + ((m + 4 * (MB)) * 2 + kh) * 512);
#define MFMA_Q(AARR, BARR_, MOFF, NOFF)                                       \
  __builtin_amdgcn_s_setprio(1);                                              \
  _Pragma("unroll") for (int kh = 0; kh < 2; ++kh)                            \
  _Pragma("unroll") for (int m = 0; m < 4; ++m)                               \
  _Pragma("unroll") for (int n = 0; n < 2; ++n)                               \
      acc[m + MOFF][n + NOFF] = __builtin_amdgcn_mfma_f32_16x16x32_bf16(      \
          AARR[m][kh], BARR_[n][kh], acc[m + MOFF][n + NOFF], 0, 0, 0);       \
  __builtin_amdgcn_s_setprio(0);

  f32x4 acc[8][4];
#pragma unroll
  for (int m = 0; m < 8; ++m)
#pragma unroll
    for (int n = 0; n < 4; ++n) {
      f32x4 zz = {0.f, 0.f, 0.f, 0.f};
      acc[m][n] = zz;
    }

  // ---- prologue: emulate steady-state issue order (virtual tiles -2,-1) ----
  {
    bf16* L0 = &LDS[0][0];
    bf16* L1 = &LDS[1][0];
    ST_B(0, 0, L0); ST_A(0, 0, L0);   // P3(-2), P4(-2)
    ST_A(0, 1, L0); ST_B(0, 1, L0);   // P1(-1), P2(-1)
    ST_B(1, 0, L1); ST_A(1, 0, L1);   // P3(-1), P4(-1)
    WAITV4;  // confirm tile0 fully; leave {B_h0(1), A_h0(1)} in flight
    BARR;
  }

#define TILE(T, CUR, NXT)                                                     \
  {                                                                           \
    const bf16* Lc = &LDS[CUR][0];                                            \
    bf16* Lcw = &LDS[CUR][0];                                                 \
    bf16* Ln = &LDS[NXT][0];                                                  \
    bf16x8 a0[4][2], a1[4][2], b0[2][2], b1[2][2];                            \
    /* P1: read a0+b0 (12); stage A_h1(t+1)->NXT; MFMA a0*b0 */               \
    RD_A(a0, Lc, 0);                                                          \
    RD_B(b0, Lc, 0);                                                          \
    ST_A((T) + 1, 1, Ln);                                                     \
    LGKM8; BARR; LGKM0;                                                       \
    MFMA_Q(a0, b0, 0, 0);                                                     \
    BARR;                                                                     \
    /* P2: read a1 (8); stage B_h1(t+1)->NXT; MFMA a1*b0 */                   \
    RD_A(a1, Lc, 1);                                                          \
    ST_B((T) + 1, 1, Ln);                                                     \
    BARR; LGKM0;                                                              \
    MFMA_Q(a1, b0, 4, 0);                                                     \
    BARR;                                                                     \
    /* P3: read b1 (4); stage B_h0(t+2)->CUR; MFMA a0*b1 */                   \
    RD_B(b1, Lc, 1);                                                          \
    ST_B((T) + 2, 0, Lcw);                                                    \
    BARR; LGKM0;                                                              \
    MFMA_Q(a0, b1, 0, 2);                                                     \
    BARR;                                                                     \
    /* P4: stage A_h0(t+2)->CUR; MFMA a1*b1; counted vmcnt */                 \
    ST_A((T) + 2, 0, Lcw);                                                    \
    BARR;                                                                     \
    MFMA_Q(a1, b1, 4, 2);                                                     \
    WAITV4;                                                                   \
    BARR;                                                                     \
  }

#pragma unroll 1
  for (int t = 0; t < NT; t += 2) {
    TILE(t, 0, 1);
    TILE(t + 1, 1, 0);
  }

  // ---- epilogue: C/D layout col=lane&15, row=(lane>>4)*4+q ----
  const int lq = (lane >> 4) << 2;
  const int lc = lane & 15;
  const int rowb = brow + wr * 128;
  const int colb = bcol + wc * 64;
  if constexpr (EPI == 0) {
    if (bcol < UNITS) {
#pragma unroll
      for (int m = 0; m < 8; ++m)
#pragma unroll
        for (int n = 0; n < 4; ++n) {
          int col = colb + n * 16 + lc;
          float ba = bias_a[col] + bias_b[col];
#pragma unroll
          for (int q = 0; q < 4; ++q) {
            int row = rowb + m * 16 + lq + q;
            zbuf[(size_t)row * UNITS + col] = (bf16)(acc[m][n][q] + ba);
          }
        }
    } else {
#pragma unroll
      for (int m = 0; m < 8; ++m)
#pragma unroll
        for (int n = 0; n < 4; ++n) {
          int col = colb - UNITS + n * 16 + lc;
          float bc = bias_c[col] + bias_d[col];
#pragma unroll
          for (int q = 0; q < 4; ++q) {
            int row = rowb + m * 16 + lq + q;
            size_t idx = (size_t)row * UNITS + col;
            float r = acc[m][n][q] + bc;
            rxbuf[idx] = (bf16)(r * xin[idx]);
          }
        }
    }
  } else {
#pragma unroll
    for (int m = 0; m < 8; ++m)
#pragma unroll
      for (int n = 0; n < 4; ++n) {
        int col = colb + n * 16 + lc;
        float bg_ = bias_a[col] + bias_b[col];
#pragma unroll
        for (int q = 0; q < 4; ++q) {
          int row = rowb + m * 16 + lq + q;
          size_t idx = (size_t)row * UNITS + col;
          float h = tanhf(acc[m][n][q] + bg_);
          float zv = (float)zbuf[idx];
          float xv = xin[idx];
          outbuf[idx] = (1.f - zv) * xv + zv * h;
        }
      }
  }
#undef ST_A
#undef ST_B
#undef RD_A
#undef RD_B
#undef MFMA_Q
#undef TILE
}

extern "C" void kernel_launch(void* const* d_in, const int* in_sizes, int n_in,
                              void* d_out, int out_size, void* d_ws, size_t ws_size,
                              hipStream_t stream) {
  const float* x   = (const float*)d_in[0];
  const float* y   = (const float*)d_in[1];
  const float* Wz  = (const float*)d_in[2];
  const float* bz  = (const float*)d_in[3];
  const float* Uz  = (const float*)d_in[4];
  const float* buz = (const float*)d_in[5];
  const float* Wr  = (const float*)d_in[6];
  const float* br  = (const float*)d_in[7];
  const float* Ur  = (const float*)d_in[8];
  const float* bur = (const float*)d_in[9];
  const float* Wg  = (const float*)d_in[10];
  const float* bg  = (const float*)d_in[11];
  const float* Ug  = (const float*)d_in[12];
  const float* bug = (const float*)d_in[13];
  float* out = (float*)d_out;

  char* w = (char*)d_ws;
  bf16* Ybf = (bf16*)w;  w += (size_t)NROWS * UNITS * 2;  // 32 MiB
  bf16* Xbf = (bf16*)w;  w += (size_t)NROWS * UNITS * 2;  // 32 MiB
  bf16* RX  = (bf16*)w;  w += (size_t)NROWS * UNITS * 2;  // 32 MiB
  bf16* Bzr = (bf16*)w;  w += (size_t)4096 * 4096 * 2;    // 32 MiB [4096 cols][K=4096]
  bf16* Bgt = (bf16*)w;  w += (size_t)2048 * 4096 * 2;    // 16 MiB [2048 cols][K=4096]
  bf16* Zb  = (bf16*)w;  w += (size_t)NROWS * UNITS * 2;  // 32 MiB

  pack_xy_kernel<<<2048, 256, 0, stream>>>(x, y, Xbf, Ybf);
  dim3 tg(64, 64, 6);
  transpose_cvt6_kernel<<<tg, 256, 0, stream>>>(Wz, Uz, Wr, Ur, Wg, Ug, Bzr, Bgt);

  // GEMM1: [8192 x 4096] = [Y|X] @ Bzr^T -> z (bf16), rx (bf16)
  gemm256<0><<<512, 512, 0, stream>>>(Ybf, Xbf, Bzr, bz, buz, br, bur, x, Zb, RX, nullptr);
  // GEMM2: [8192 x 2048] = [Y|RX] @ Bg^T -> out
  gemm256<1><<<256, 512, 0, stream>>>(Ybf, RX, Bgt, bg, bug, nullptr, nullptr, x, Zb, nullptr, out);
}